// Round 7
// baseline (118.372 us; speedup 1.0000x reference)
//
#include <hip/hip_runtime.h>
#include <math.h>

// B=16384, S=64, V=25, E=64, H=64, 4H=256, C=3
// Barrier-free LSTM: 1 wave owns 16 batch rows x all 64 h-units.
// gates^T = W_fused @ x^T via mfma_f32_16x16x32_bf16, A = weights (VGPR-stationary).
// K = 3 chunks of 32: ch0 = msg k=0..24 (+bias row k=25), ch1/2 = h with PERMUTED k:
//   unit(ch,kappa) = (ch-1)*32 + ( (kappa&7)<4 ? 4*(kappa>>3)+(kappa&3)
//                                              : 16+4*(kappa>>3)+((kappa&7)-4) )
// With this permutation, each lane's produced h-units (C-layout rows 4*lq+q of
// u-group tiles) are exactly its consumed B-fragment slice (k=8*lq+j) -> the
// recurrence is fully lane-local: no LDS, no barriers, no cross-lane ops.

using bf16x8 = __attribute__((ext_vector_type(8))) short;
using f32x4  = __attribute__((ext_vector_type(4))) float;

union U16B { uint4 u; bf16x8 v; };

#define KE  1.4426950408889634f
#define K2E 2.8853900817779268f

__device__ __forceinline__ unsigned short f2bf(float x) {
    unsigned int u = __float_as_uint(x);
    u += 0x7FFFu + ((u >> 16) & 1u);           // RNE
    return (unsigned short)(u >> 16);
}
__device__ __forceinline__ float bf2f(unsigned short h) {
    return __uint_as_float(((unsigned int)h) << 16);
}

// A-fragment: lane holds A[row=lane&15][kappa=(lane>>4)*8+j], j=0..7.
// wfrag[((ch*16+gt)*64+lane)*8+j]; tile gt covers gunits [16gt,16gt+16).
// ch0: combT[gunit][k] (k<25), k==25 -> bias; ch1/2: Whh[gunit][unit(ch,kappa)].
// All pre-scaled: gate=gunit>>6; s = (gate==2)? +K2E : -KE.
__global__ void prep_kernel(const float* __restrict__ emb,
                            const float* __restrict__ Wih,
                            const float* __restrict__ Whh,
                            const float* __restrict__ bih,
                            const float* __restrict__ bhh,
                            unsigned short* __restrict__ wfrag) {
    const int b = blockIdx.x, tid = threadIdx.x;
    const int ch = b >> 4, gt = b & 15;
    const int lane = tid >> 3, j = tid & 7;
    const int kloc = (lane >> 4) * 8 + j;       // kappa 0..31
    const int gunit = 16 * gt + (lane & 15);    // 0..255
    float v = 0.f;
    if (ch == 0) {
        if (kloc < 25) {
            const float* ep = emb + kloc * 64;
            const float* wp = Wih + gunit * 64;
            float s = 0.f;
            #pragma unroll
            for (int e = 0; e < 64; ++e) s = fmaf(ep[e], wp[e], s);
            v = s;
        } else if (kloc == 25) {
            v = bih[gunit] + bhh[gunit];        // bias row
        }
    } else {
        const int jj = kloc & 7, lqk = kloc >> 3;
        const int unit = (ch - 1) * 32 +
            ((jj < 4) ? (4 * lqk + jj) : (16 + 4 * lqk + (jj - 4)));
        v = Whh[gunit * 64 + unit];
    }
    const int gate = gunit >> 6;
    const float s = (gate == 2) ? K2E : -KE;
    wfrag[((ch * 16 + gt) * 64 + lane) * 8 + j] = f2bf(s * v);
}

#define CVTPK(D, A, B_)                                                      \
    asm("v_cvt_pk_bf16_f32 %0, %1, %2" : "=v"(D) : "v"(A), "v"(B_));

#define LOADMSG(DST, SS)                                                     \
    {                                                                        \
        const float* p_ = mrow + (SS) * 25 + kq;                             \
        if (kq < 24) {                                                       \
            float t0_ = p_[0], t1_ = p_[1], t2_ = p_[2], t3_ = p_[3];        \
            float t4_ = p_[4], t5_ = p_[5], t6_ = p_[6], t7_ = p_[7];        \
            CVTPK(DST.u.x, t0_, t1_) CVTPK(DST.u.y, t2_, t3_)                \
            CVTPK(DST.u.z, t4_, t5_) CVTPK(DST.u.w, t6_, t7_)                \
        } else {                                                             \
            float t0_ = p_[0], one_ = 1.0f;                                  \
            CVTPK(DST.u.x, t0_, one_)                                        \
            DST.u.y = 0u; DST.u.z = 0u; DST.u.w = 0u;                        \
        }                                                                    \
    }

// BHC/BHN: U16B[2] (current / next h B-fragments). All lane-local.
#define STEP(S, MC, MN, BHC, BHN)                                            \
    {                                                                        \
        if ((S) < 63) LOADMSG(MN, (S) + 1)                                   \
        f32x4 acc[4][4];                                                     \
        _Pragma("unroll") for (int u = 0; u < 4; ++u)                        \
            _Pragma("unroll") for (int i = 0; i < 4; ++i)                    \
                acc[u][i] = (f32x4){0.f, 0.f, 0.f, 0.f};                     \
        _Pragma("unroll") for (int u = 0; u < 4; ++u)                        \
            _Pragma("unroll") for (int i = 0; i < 4; ++i)                    \
                acc[u][i] = __builtin_amdgcn_mfma_f32_16x16x32_bf16(         \
                    w[4 * i + u], MC.v, acc[u][i], 0, 0, 0);                 \
        _Pragma("unroll") for (int u = 0; u < 4; ++u)                        \
            _Pragma("unroll") for (int i = 0; i < 4; ++i)                    \
                acc[u][i] = __builtin_amdgcn_mfma_f32_16x16x32_bf16(         \
                    w[16 + 4 * i + u], BHC[0].v, acc[u][i], 0, 0, 0);        \
        _Pragma("unroll") for (int u = 0; u < 4; ++u)                        \
            _Pragma("unroll") for (int i = 0; i < 4; ++i)                    \
                acc[u][i] = __builtin_amdgcn_mfma_f32_16x16x32_bf16(         \
                    w[32 + 4 * i + u], BHC[1].v, acc[u][i], 0, 0, 0);        \
        _Pragma("unroll") for (int u = 0; u < 4; ++u) {                      \
            float hn[4];                                                     \
            _Pragma("unroll") for (int q = 0; q < 4; ++q) {                  \
                float ai = acc[u][0][q], af = acc[u][1][q];                  \
                float ag = acc[u][2][q], ao = acc[u][3][q];                  \
                float ti = __builtin_amdgcn_exp2f(ai);                       \
                float tf = __builtin_amdgcn_exp2f(af);                       \
                float to = __builtin_amdgcn_exp2f(ao);                       \
                float tg = __builtin_amdgcn_exp2f(-fabsf(ag));               \
                float ig = (1.f - tg) *                                      \
                    __builtin_amdgcn_rcpf((1.f + ti) * (1.f + tg));          \
                ig = copysignf(ig, ag);                                      \
                float fg = __builtin_amdgcn_rcpf(1.f + tf);                  \
                float cn = fmaf(fg, c[u][q], ig);                            \
                c[u][q] = cn;                                                \
                float tc = __builtin_amdgcn_exp2f(-fabsf(K2E * cn));         \
                float ot = (1.f - tc) *                                      \
                    __builtin_amdgcn_rcpf((1.f + to) * (1.f + tc));          \
                hn[q] = copysignf(ot, cn);                                   \
            }                                                                \
            unsigned pa_, pb_;                                               \
            CVTPK(pa_, hn[0], hn[1]) CVTPK(pb_, hn[2], hn[3])                \
            if (u == 0) { BHN[0].u.x = pa_; BHN[0].u.y = pb_; }              \
            if (u == 1) { BHN[0].u.z = pa_; BHN[0].u.w = pb_; }              \
            if (u == 2) { BHN[1].u.x = pa_; BHN[1].u.y = pb_; }              \
            if (u == 3) { BHN[1].u.z = pa_; BHN[1].u.w = pb_; }              \
        }                                                                    \
    }

__global__ __launch_bounds__(64, 1) void lstm_mfma(
    const float* __restrict__ msgs,
    const unsigned short* __restrict__ wfrag,
    const float* __restrict__ fcw,
    const float* __restrict__ fcb,
    float* __restrict__ out)
{
    const int lane = threadIdx.x;               // 0..63
    const int l16  = lane & 15;                 // batch row within tile
    const int lq   = lane >> 4;                 // lane quad
    const int row0 = blockIdx.x * 16;
    const int kq   = lq * 8;

    // all 48 weight A-fragments VGPR-resident (192 VGPRs)
    bf16x8 w[48];
    #pragma unroll
    for (int t = 0; t < 48; ++t)
        w[t] = *(const bf16x8*)(wfrag + (t * 64 + lane) * 8);

    float c[4][4];
    #pragma unroll
    for (int u = 0; u < 4; ++u)
        #pragma unroll
        for (int q = 0; q < 4; ++q) c[u][q] = 0.f;

    U16B bhA[2], bhB[2];
    bhA[0].u = make_uint4(0u, 0u, 0u, 0u);
    bhA[1].u = make_uint4(0u, 0u, 0u, 0u);

    const float* mrow = msgs + (long)(row0 + l16) * 1600;

    U16B m0, m1;
    LOADMSG(m0, 0)

    for (int s2 = 0; s2 < 64; s2 += 2) {
        STEP(s2,     m0, m1, bhA, bhB)
        STEP(s2 + 1, m1, m0, bhB, bhA)
    }
    // final h (step 63 output) is in bhA, bf16-packed, lane-local.

    // FC epilogue: lane's units are n = 16*g + 4*lq + q (g=0..3).
    float a0 = 0.f, a1 = 0.f, a2 = 0.f;
    #pragma unroll
    for (int g = 0; g < 4; ++g) {
        #pragma unroll
        for (int q = 0; q < 4; ++q) {
            unsigned uw = (g & 1) ? ((q >> 1) ? bhA[g >> 1].u.w : bhA[g >> 1].u.z)
                                  : ((q >> 1) ? bhA[g >> 1].u.y : bhA[g >> 1].u.x);
            float hv = (q & 1) ? __uint_as_float(uw & 0xFFFF0000u)
                               : __uint_as_float(uw << 16);
            int n = 16 * g + 4 * lq + q;
            a0 = fmaf(hv, fcw[n], a0);
            a1 = fmaf(hv, fcw[64 + n], a1);
            a2 = fmaf(hv, fcw[128 + n], a2);
        }
    }
    #pragma unroll
    for (int mask = 16; mask <= 32; mask <<= 1) {
        a0 += __shfl_xor(a0, mask, 64);
        a1 += __shfl_xor(a1, mask, 64);
        a2 += __shfl_xor(a2, mask, 64);
    }
    if (lq == 0) {
        float* op = out + (long)(row0 + l16) * 3;
        op[0] = a0 + fcb[0];
        op[1] = a1 + fcb[1];
        op[2] = a2 + fcb[2];
    }
}

extern "C" void kernel_launch(void* const* d_in, const int* in_sizes, int n_in,
                              void* d_out, int out_size, void* d_ws, size_t ws_size,
                              hipStream_t stream) {
    const float* msgs = (const float*)d_in[0];
    const float* emb  = (const float*)d_in[1];
    const float* Wih  = (const float*)d_in[2];
    const float* Whh  = (const float*)d_in[3];
    const float* bih  = (const float*)d_in[4];
    const float* bhh  = (const float*)d_in[5];
    const float* fcw  = (const float*)d_in[6];
    const float* fcb  = (const float*)d_in[7];
    float* out = (float*)d_out;

    // ws: wfrag bf16[48*64*8] = 49152 B
    unsigned short* wfrag = (unsigned short*)d_ws;

    prep_kernel<<<48, 512, 0, stream>>>(emb, Wih, Whh, bih, bhh, wfrag);
    lstm_mfma<<<16384 / 16, 64, 0, stream>>>(msgs, wfrag, fcw, fcb, out);
}